// Round 2
// baseline (2492.330 us; speedup 1.0000x reference)
//
#include <hip/hip_runtime.h>
#include <math.h>

#define NNODES 20000
#define NEDGES 320000
#define RREL 8
#define GDIM 256
#define EPSBN 1e-5f

typedef float f32x4 __attribute__((ext_vector_type(4)));
typedef __bf16 bf16x8 __attribute__((ext_vector_type(8)));
typedef unsigned short u16x8 __attribute__((ext_vector_type(8)));

static __device__ __forceinline__ unsigned short f2bf(float f) {
    unsigned int x = __builtin_bit_cast(unsigned int, f);
    unsigned int r = x + 0x7FFFu + ((x >> 16) & 1u);
    return (unsigned short)(r >> 16);
}
static __device__ __forceinline__ float bf2f(unsigned short u) {
    unsigned int x = ((unsigned int)u) << 16;
    return __builtin_bit_cast(float, x);
}

// ---------------- degree count / inverse ----------------
__global__ __launch_bounds__(256) void k_count(const int* __restrict__ dst, const int* __restrict__ et,
                                               int* __restrict__ cnt) {
    int e = blockIdx.x * 256 + threadIdx.x;
    if (e >= NEDGES) return;
    atomicAdd(&cnt[dst[e] * RREL + et[e]], 1);
}

__global__ __launch_bounds__(256) void k_inv(const int* __restrict__ cnt, float* __restrict__ inv) {
    int i = blockIdx.x * 256 + threadIdx.x;
    if (i >= NNODES * RREL) return;
    int c = cnt[i];
    inv[i] = 1.0f / (float)(c > 0 ? c : 1);
}

// ---------------- weight prep (transpose + bf16) ----------------
// Brel[col][g] = Wrel[r][g][h], col = r*256+h   (for Yall = x @ Wrel_cat)
__global__ __launch_bounds__(256) void k_prepBrel(const float* __restrict__ Wrel, unsigned short* __restrict__ B) {
    int idx = blockIdx.x * 256 + threadIdx.x;
    if (idx >= 2048 * 256) return;
    int col = idx >> 8, g = idx & 255;
    int r = col >> 8, h = col & 255;
    B[idx] = f2bf(Wrel[(size_t)r * 65536 + (size_t)g * 256 + h]);
}

// Broot[h][g] = Wroot[g][h]
__global__ __launch_bounds__(256) void k_prepBroot(const float* __restrict__ Wroot, unsigned short* __restrict__ B) {
    int idx = blockIdx.x * 256 + threadIdx.x;
    if (idx >= 256 * 256) return;
    int h = idx >> 8, g = idx & 255;
    B[idx] = f2bf(Wroot[(size_t)g * 256 + h]);
}

__global__ __launch_bounds__(256) void k_prepB2(const float* __restrict__ Wq, const float* __restrict__ Wk,
                                                const float* __restrict__ Wv, const float* __restrict__ Ws,
                                                const float* __restrict__ bq, const float* __restrict__ bk,
                                                const float* __restrict__ bv, const float* __restrict__ bs,
                                                unsigned short* __restrict__ B2t, float* __restrict__ bias2) {
    int idx = blockIdx.x * 256 + threadIdx.x;
    if (idx >= 1024 * 256) return;
    int c = idx / 256, g = idx % 256;
    const float* W = (c < 256) ? Wq : (c < 512) ? Wk : (c < 768) ? Wv : Ws;
    int cc = c & 255;
    B2t[idx] = f2bf(W[(size_t)g * 256 + cc]);
    if (g == 0) {
        const float* B = (c < 256) ? bq : (c < 512) ? bk : (c < 768) ? bv : bs;
        bias2[c] = B[cc];
    }
}

// ---------------- bf16 MFMA GEMM ----------------
// C[M,Ncols] = A[M,K](f32, converted) * Bt[Ncols,K](bf16)^T  (+ bias, + add, per MODE)
// MODE 0: f32 out = acc + bias
// MODE 1: f32 out = acc + bias + addin   (addin may alias C; same-thread RAW only)
// MODE 2: bf16 out = acc                 (no bias)
// MODE 3: split f32 out: col<768 -> C[row*768+col], col>=768 -> C2[row*256+col-768]; + bias
#define BM 64
#define BN 64
#define BK 32
template<int MODE>
__global__ __launch_bounds__(256) void k_gemm(const float* __restrict__ A, const unsigned short* __restrict__ Bt,
                                              const float* __restrict__ bias, const float* __restrict__ addin,
                                              void* __restrict__ Cv, float* __restrict__ C2,
                                              int M, int K, int Ncols) {
    __shared__ unsigned short As[BM][BK + 8];
    __shared__ unsigned short Bs[BN][BK + 8];
    int tid = threadIdx.x;
    int lane = tid & 63, wid = tid >> 6;
    int wr = wid >> 1, wc = wid & 1;
    int lr = lane & 15, lq = lane >> 4;
    int brow = blockIdx.x * BM, bcol = blockIdx.y * BN;
    int sRow = tid >> 2;          // 0..63
    int sKb = (tid & 3) * 8;      // 0,8,16,24

    f32x4 acc00 = {0.f, 0.f, 0.f, 0.f}, acc01 = acc00, acc10 = acc00, acc11 = acc00;

    for (int k0 = 0; k0 < K; k0 += BK) {
        {
            int grow = brow + sRow;
            float vals[8];
            if (grow < M) {
                const float* p = A + (size_t)grow * K + k0 + sKb;
                float4 v0 = ((const float4*)p)[0];
                float4 v1 = ((const float4*)p)[1];
                vals[0] = v0.x; vals[1] = v0.y; vals[2] = v0.z; vals[3] = v0.w;
                vals[4] = v1.x; vals[5] = v1.y; vals[6] = v1.z; vals[7] = v1.w;
            } else {
                #pragma unroll
                for (int i = 0; i < 8; i++) vals[i] = 0.f;
            }
            u16x8 w;
            #pragma unroll
            for (int i = 0; i < 8; i++) w[i] = f2bf(vals[i]);
            *(u16x8*)&As[sRow][sKb] = w;
        }
        {
            const u16x8* p = (const u16x8*)(Bt + (size_t)(bcol + sRow) * K + k0 + sKb);
            *(u16x8*)&Bs[sRow][sKb] = *p;
        }
        __syncthreads();
        bf16x8 a0 = *(const bf16x8*)&As[wr * 32 + lr][lq * 8];
        bf16x8 a1 = *(const bf16x8*)&As[wr * 32 + 16 + lr][lq * 8];
        bf16x8 b0 = *(const bf16x8*)&Bs[wc * 32 + lr][lq * 8];
        bf16x8 b1 = *(const bf16x8*)&Bs[wc * 32 + 16 + lr][lq * 8];
        acc00 = __builtin_amdgcn_mfma_f32_16x16x32_bf16(a0, b0, acc00, 0, 0, 0);
        acc01 = __builtin_amdgcn_mfma_f32_16x16x32_bf16(a0, b1, acc01, 0, 0, 0);
        acc10 = __builtin_amdgcn_mfma_f32_16x16x32_bf16(a1, b0, acc10, 0, 0, 0);
        acc11 = __builtin_amdgcn_mfma_f32_16x16x32_bf16(a1, b1, acc11, 0, 0, 0);
        __syncthreads();
    }
    // C/D layout: col = lane&15, row = (lane>>4)*4 + reg   [measured m89]
    f32x4 accs[2][2] = {{acc00, acc01}, {acc10, acc11}};
    #pragma unroll
    for (int rm = 0; rm < 2; rm++) {
        #pragma unroll
        for (int cn = 0; cn < 2; cn++) {
            int row = brow + wr * 32 + rm * 16 + lq * 4;
            int col = bcol + wc * 32 + cn * 16 + lr;
            #pragma unroll
            for (int r = 0; r < 4; r++) {
                if (row + r >= M) continue;
                float v = accs[rm][cn][r];
                if (MODE == 2) {
                    ((unsigned short*)Cv)[(size_t)(row + r) * Ncols + col] = f2bf(v);
                } else {
                    v += bias[col];
                    if (MODE == 1) v += addin[(size_t)(row + r) * Ncols + col];
                    if (MODE == 3) {
                        if (col < 768) ((float*)Cv)[(size_t)(row + r) * 768 + col] = v;
                        else           C2[(size_t)(row + r) * 256 + (col - 768)] = v;
                    } else {
                        ((float*)Cv)[(size_t)(row + r) * Ncols + col] = v;
                    }
                }
            }
        }
    }
}

// ---------------- RGCN scatter: agg[dst] += inv[dst,r] * Yall[src, r*256..] ----------------
__global__ __launch_bounds__(256) void k_scatter(const unsigned short* __restrict__ Yall, const int* __restrict__ src,
                                                 const int* __restrict__ dst, const int* __restrict__ et,
                                                 const float* __restrict__ inv, float* __restrict__ agg) {
    int gid = blockIdx.x * 256 + threadIdx.x;
    int e = gid >> 6, lane = gid & 63;
    if (e >= NEDGES) return;
    int s = src[e], d = dst[e], r = et[e];
    float sc = inv[d * RREL + r];
    const unsigned short* yp = Yall + (size_t)s * 2048 + r * 256 + lane * 4;
    ushort4 y = *(const ushort4*)yp;
    float* o = agg + (size_t)d * 256 + lane * 4;
    atomicAdd(o + 0, bf2f(y.x) * sc);
    atomicAdd(o + 1, bf2f(y.y) * sc);
    atomicAdd(o + 2, bf2f(y.z) * sc);
    atomicAdd(o + 3, bf2f(y.w) * sc);
}

// ---------------- attention ----------------
__global__ __launch_bounds__(256) void k_logits(const float* __restrict__ QKV, const int* __restrict__ src,
                                                const int* __restrict__ dst, float* __restrict__ logits,
                                                unsigned int* __restrict__ mmax) {
    int gid = blockIdx.x * 256 + threadIdx.x;
    int e = gid >> 6, lane = gid & 63;
    if (e >= NEDGES) return;
    int s = src[e], d = dst[e];
    float4 q = ((const float4*)(QKV + (size_t)d * 768))[lane];
    float4 k = ((const float4*)(QKV + (size_t)s * 768 + 256))[lane];
    float p = q.x * k.x + q.y * k.y + q.z * k.z + q.w * k.w;
    #pragma unroll
    for (int o = 32; o; o >>= 1) p += __shfl_xor(p, o);
    if (lane == 0) {
        float lg = p * 0.0625f;
        logits[e] = lg;
        int ib = __float_as_int(lg);
        unsigned int key = (ib >= 0) ? ((unsigned int)ib | 0x80000000u) : ~(unsigned int)ib;
        atomicMax(&mmax[d], key);
    }
}

__global__ __launch_bounds__(256) void k_exp(const int* __restrict__ dst, float* __restrict__ logits,
                                             const unsigned int* __restrict__ mmax, float* __restrict__ den) {
    int e = blockIdx.x * 256 + threadIdx.x;
    if (e >= NEDGES) return;
    int d = dst[e];
    unsigned int key = mmax[d];
    int ib = (key & 0x80000000u) ? (int)(key ^ 0x80000000u) : (int)~key;
    float m = __int_as_float(ib);
    float ex = expf(logits[e] - m);
    logits[e] = ex;
    atomicAdd(&den[d], ex);
}

__global__ __launch_bounds__(256) void k_attnout(const float* __restrict__ QKV, const int* __restrict__ src,
                                                 const int* __restrict__ dst, const float* __restrict__ ex,
                                                 const float* __restrict__ den, float* __restrict__ out) {
    int gid = blockIdx.x * 256 + threadIdx.x;
    int e = gid >> 6, lane = gid & 63;
    if (e >= NEDGES) return;
    int s = src[e], d = dst[e];
    float alpha = ex[e] / fmaxf(den[d], 1e-16f);
    float4 v = ((const float4*)(QKV + (size_t)s * 768 + 512))[lane];
    float* o = out + (size_t)d * 256 + lane * 4;
    atomicAdd(o + 0, alpha * v.x);
    atomicAdd(o + 1, alpha * v.y);
    atomicAdd(o + 2, alpha * v.z);
    atomicAdd(o + 3, alpha * v.w);
}

// ---------------- batch norm + leaky relu ----------------
__global__ __launch_bounds__(256) void k_bnstats(const float* __restrict__ out, float* __restrict__ sums,
                                                 float* __restrict__ sumsq) {
    int c = threadIdx.x;
    int rows_per = (NNODES + gridDim.x - 1) / gridDim.x;
    int r0 = blockIdx.x * rows_per;
    int r1 = r0 + rows_per; if (r1 > NNODES) r1 = NNODES;
    float s = 0.f, ss = 0.f;
    for (int r = r0; r < r1; r++) {
        float v = out[(size_t)r * 256 + c];
        s += v; ss += v * v;
    }
    atomicAdd(&sums[c], s);
    atomicAdd(&sumsq[c], ss);
}

__global__ __launch_bounds__(256) void k_bnfinal(const float* __restrict__ sums, const float* __restrict__ sumsq,
                                                 const float* __restrict__ gamma, const float* __restrict__ beta,
                                                 float* __restrict__ scale, float* __restrict__ shift) {
    int c = threadIdx.x;
    float mu = sums[c] * (1.0f / NNODES);
    float var = sumsq[c] * (1.0f / NNODES) - mu * mu;
    float sc = gamma[c] * rsqrtf(fmaxf(var, 0.f) + EPSBN);
    scale[c] = sc;
    shift[c] = beta[c] - mu * sc;
}

__global__ __launch_bounds__(256) void k_bnapply(float4* __restrict__ out, const float* __restrict__ scale,
                                                 const float* __restrict__ shift) {
    int i = blockIdx.x * 256 + threadIdx.x;
    if (i >= NNODES * 64) return;
    int c4 = i & 63;
    float4 v = out[i];
    float4 s4 = ((const float4*)scale)[c4];
    float4 h4 = ((const float4*)shift)[c4];
    v.x = v.x * s4.x + h4.x; v.y = v.y * s4.y + h4.y;
    v.z = v.z * s4.z + h4.z; v.w = v.w * s4.w + h4.w;
    v.x = v.x > 0.f ? v.x : 0.01f * v.x;
    v.y = v.y > 0.f ? v.y : 0.01f * v.y;
    v.z = v.z > 0.f ? v.z : 0.01f * v.z;
    v.w = v.w > 0.f ? v.w : 0.01f * v.w;
    out[i] = v;
}

extern "C" void kernel_launch(void* const* d_in, const int* in_sizes, int n_in,
                              void* d_out, int out_size, void* d_ws, size_t ws_size,
                              hipStream_t stream) {
    const float* x = (const float*)d_in[0];
    const int* ei = (const int*)d_in[1];
    const int* etype = (const int*)d_in[2];
    const float* Wrel = (const float*)d_in[3];
    const float* Wroot = (const float*)d_in[4];
    const float* b1 = (const float*)d_in[5];
    const float* Wq = (const float*)d_in[6];
    const float* bq = (const float*)d_in[7];
    const float* Wk = (const float*)d_in[8];
    const float* bk = (const float*)d_in[9];
    const float* Wv = (const float*)d_in[10];
    const float* bv = (const float*)d_in[11];
    const float* Ws = (const float*)d_in[12];
    const float* bs = (const float*)d_in[13];
    const float* gamma = (const float*)d_in[14];
    const float* beta = (const float*)d_in[15];
    float* out = (float*)d_out;

    const int* srcA = ei;
    const int* dstA = ei + NEDGES;

    // ---- workspace layout (all 16B-aligned) ----
    char* w = (char*)d_ws;
    unsigned short* Yall = (unsigned short*)w;  w += (size_t)NNODES * 2048 * 2;  //  81.92 MB
    float* agg = (float*)w;                     w += (size_t)NNODES * 256 * 4;   //  20.48 MB (reused as x1)
    float* QKV = (float*)w;                     w += (size_t)NNODES * 768 * 4;   //  61.44 MB
    unsigned short* Brel = (unsigned short*)w;  w += (size_t)2048 * 256 * 2;     //   1.05 MB
    unsigned short* Broot = (unsigned short*)w; w += (size_t)256 * 256 * 2;      //   0.13 MB
    unsigned short* B2t = (unsigned short*)w;   w += (size_t)1024 * 256 * 2;     //   0.52 MB
    float* bias2 = (float*)w;                   w += 1024 * 4;
    int* cnt = (int*)w;                         w += (size_t)NNODES * RREL * 4;
    float* invc = (float*)w;                    w += (size_t)NNODES * RREL * 4;
    float* logits = (float*)w;                  w += (size_t)NEDGES * 4;
    unsigned int* mmax = (unsigned int*)w;      w += (size_t)NNODES * 4;
    float* den = (float*)w;                     w += (size_t)NNODES * 4;
    float* sums = (float*)w;                    w += 1024;
    float* sumsq = (float*)w;                   w += 1024;
    float* scale = (float*)w;                   w += 1024;
    float* shift = (float*)w;                   w += 1024;
    size_t need = (size_t)(w - (char*)d_ws);
    if (ws_size < need) return;  // turn would-be OOB fault into a clean validation failure

    hipMemsetAsync(cnt, 0, (size_t)NNODES * RREL * 4, stream);
    hipMemsetAsync(agg, 0, (size_t)NNODES * 256 * 4, stream);
    hipMemsetAsync(mmax, 0, (size_t)NNODES * 4, stream);
    hipMemsetAsync(den, 0, (size_t)NNODES * 4, stream);
    hipMemsetAsync(sums, 0, 1024, stream);
    hipMemsetAsync(sumsq, 0, 1024, stream);

    k_count<<<(NEDGES + 255) / 256, 256, 0, stream>>>(dstA, etype, cnt);
    k_inv<<<(NNODES * RREL + 255) / 256, 256, 0, stream>>>(cnt, invc);
    k_prepBrel<<<(2048 * 256 + 255) / 256, 256, 0, stream>>>(Wrel, Brel);
    k_prepBroot<<<(256 * 256 + 255) / 256, 256, 0, stream>>>(Wroot, Broot);
    k_prepB2<<<(1024 * 256 + 255) / 256, 256, 0, stream>>>(Wq, Wk, Wv, Ws, bq, bk, bv, bs, B2t, bias2);

    // Yall[N,2048] (bf16) = x @ [W_0|...|W_7]
    dim3 gA((NNODES + BM - 1) / BM, 2048 / BN);
    k_gemm<2><<<gA, 256, 0, stream>>>(x, Brel, nullptr, nullptr, (void*)Yall, nullptr, NNODES, 256, 2048);

    // agg[dst] += inv * Yall[src, r]
    k_scatter<<<(NEDGES * 64 + 255) / 256, 256, 0, stream>>>(Yall, srcA, dstA, etype, invc, agg);

    // x1 = x @ W_root + b1 + agg   (in place over agg)
    dim3 gB((NNODES + BM - 1) / BM, 256 / BN);
    k_gemm<1><<<gB, 256, 0, stream>>>(x, Broot, b1, agg, (void*)agg, nullptr, NNODES, 256, 256);
    float* x1 = agg;

    // [q|k|v -> QKV, skip -> out] = x1 @ [Wq|Wk|Wv|Wskip] + bias2
    dim3 gC((NNODES + BM - 1) / BM, 1024 / BN);
    k_gemm<3><<<gC, 256, 0, stream>>>(x1, B2t, bias2, nullptr, (void*)QKV, out, NNODES, 256, 1024);

    k_logits<<<(NEDGES * 64 + 255) / 256, 256, 0, stream>>>(QKV, srcA, dstA, logits, mmax);
    k_exp<<<(NEDGES + 255) / 256, 256, 0, stream>>>(dstA, logits, mmax, den);
    k_attnout<<<(NEDGES * 64 + 255) / 256, 256, 0, stream>>>(QKV, srcA, dstA, logits, den, out);

    k_bnstats<<<200, 256, 0, stream>>>(out, sums, sumsq);
    k_bnfinal<<<1, 256, 0, stream>>>(sums, sumsq, gamma, beta, scale, shift);
    k_bnapply<<<(NNODES * 64 + 255) / 256, 256, 0, stream>>>((float4*)out, scale, shift);
}

// Round 3
// 469.060 us; speedup vs baseline: 5.3135x; 5.3135x over previous
//
#include <hip/hip_runtime.h>
#include <math.h>

#define NNODES 20000
#define NEDGES 320000
#define RREL 8
#define GDIM 256
#define EPSBN 1e-5f

typedef float f32x4 __attribute__((ext_vector_type(4)));
typedef __bf16 bf16x8 __attribute__((ext_vector_type(8)));
typedef unsigned short u16x8 __attribute__((ext_vector_type(8)));

static __device__ __forceinline__ unsigned short f2bf(float f) {
    unsigned int x = __builtin_bit_cast(unsigned int, f);
    unsigned int r = x + 0x7FFFu + ((x >> 16) & 1u);
    return (unsigned short)(r >> 16);
}
static __device__ __forceinline__ float bf2f(unsigned short u) {
    unsigned int x = ((unsigned int)u) << 16;
    return __builtin_bit_cast(float, x);
}

// ---------------- degree count / inverse ----------------
__global__ __launch_bounds__(256) void k_count(const int* __restrict__ dst, const int* __restrict__ et,
                                               int* __restrict__ cnt) {
    int e = blockIdx.x * 256 + threadIdx.x;
    if (e >= NEDGES) return;
    atomicAdd(&cnt[dst[e] * RREL + et[e]], 1);
}

__global__ __launch_bounds__(256) void k_inv(const int* __restrict__ cnt, float* __restrict__ inv) {
    int i = blockIdx.x * 256 + threadIdx.x;
    if (i >= NNODES * RREL) return;
    int c = cnt[i];
    inv[i] = 1.0f / (float)(c > 0 ? c : 1);
}

__global__ __launch_bounds__(256) void k_degsum(const int* __restrict__ cnt, int* __restrict__ deg) {
    int i = blockIdx.x * 256 + threadIdx.x;
    if (i >= NNODES) return;
    const int4* p = (const int4*)(cnt + i * 8);
    int4 a = p[0], b = p[1];
    deg[i] = a.x + a.y + a.z + a.w + b.x + b.y + b.z + b.w;
}

// single-block exclusive scan over deg[0..NNODES) -> start, cursor
__global__ __launch_bounds__(256) void k_scan(const int* __restrict__ deg, int* __restrict__ start,
                                              int* __restrict__ cursor) {
    __shared__ int part[256];
    int t = threadIdx.x;
    const int chunk = (NNODES + 255) / 256;  // 79
    int i0 = t * chunk, i1 = i0 + chunk;
    if (i1 > NNODES) i1 = NNODES;
    int s = 0;
    for (int i = i0; i < i1; i++) s += deg[i];
    part[t] = s;
    __syncthreads();
    if (t == 0) {
        int acc = 0;
        for (int j = 0; j < 256; j++) { int v = part[j]; part[j] = acc; acc += v; }
    }
    __syncthreads();
    int acc = part[t];
    for (int i = i0; i < i1; i++) { start[i] = acc; cursor[i] = acc; acc += deg[i]; }
}

// csr[pos] = src*8 + et, grouped by dst
__global__ __launch_bounds__(256) void k_fill(const int* __restrict__ src, const int* __restrict__ dst,
                                              const int* __restrict__ et, int* __restrict__ cursor,
                                              int* __restrict__ csr) {
    int e = blockIdx.x * 256 + threadIdx.x;
    if (e >= NEDGES) return;
    int pos = atomicAdd(&cursor[dst[e]], 1);
    csr[pos] = src[e] * 8 + et[e];
}

// ---------------- weight prep (transpose + bf16) ----------------
__global__ __launch_bounds__(256) void k_prepBrel(const float* __restrict__ Wrel, unsigned short* __restrict__ B) {
    int idx = blockIdx.x * 256 + threadIdx.x;
    if (idx >= 2048 * 256) return;
    int col = idx >> 8, g = idx & 255;
    int r = col >> 8, h = col & 255;
    B[idx] = f2bf(Wrel[(size_t)r * 65536 + (size_t)g * 256 + h]);
}

__global__ __launch_bounds__(256) void k_prepBroot(const float* __restrict__ Wroot, unsigned short* __restrict__ B) {
    int idx = blockIdx.x * 256 + threadIdx.x;
    if (idx >= 256 * 256) return;
    int h = idx >> 8, g = idx & 255;
    B[idx] = f2bf(Wroot[(size_t)g * 256 + h]);
}

__global__ __launch_bounds__(256) void k_prepB2(const float* __restrict__ Wq, const float* __restrict__ Wk,
                                                const float* __restrict__ Wv, const float* __restrict__ Ws,
                                                const float* __restrict__ bq, const float* __restrict__ bk,
                                                const float* __restrict__ bv, const float* __restrict__ bs,
                                                unsigned short* __restrict__ B2t, float* __restrict__ bias2) {
    int idx = blockIdx.x * 256 + threadIdx.x;
    if (idx >= 1024 * 256) return;
    int c = idx / 256, g = idx % 256;
    const float* W = (c < 256) ? Wq : (c < 512) ? Wk : (c < 768) ? Wv : Ws;
    int cc = c & 255;
    B2t[idx] = f2bf(W[(size_t)g * 256 + cc]);
    if (g == 0) {
        const float* B = (c < 256) ? bq : (c < 512) ? bk : (c < 768) ? bv : bs;
        bias2[c] = B[cc];
    }
}

// ---------------- bf16 MFMA GEMM ----------------
// MODE 1: f32 out = acc + bias + addin (addin aliases C)
// MODE 2: bf16 out = acc
// MODE 3: split f32: col<768 -> C[row*768+col], col>=768 -> C2[row*256+col-768]; + bias
#define BM 64
#define BN 64
#define BK 32
template<int MODE>
__global__ __launch_bounds__(256) void k_gemm(const float* __restrict__ A, const unsigned short* __restrict__ Bt,
                                              const float* __restrict__ bias, const float* __restrict__ addin,
                                              void* __restrict__ Cv, float* __restrict__ C2,
                                              int M, int K, int Ncols) {
    __shared__ unsigned short As[BM][BK + 8];
    __shared__ unsigned short Bs[BN][BK + 8];
    int tid = threadIdx.x;
    int lane = tid & 63, wid = tid >> 6;
    int wr = wid >> 1, wc = wid & 1;
    int lr = lane & 15, lq = lane >> 4;
    int brow = blockIdx.x * BM, bcol = blockIdx.y * BN;
    int sRow = tid >> 2;
    int sKb = (tid & 3) * 8;

    f32x4 acc00 = {0.f, 0.f, 0.f, 0.f}, acc01 = acc00, acc10 = acc00, acc11 = acc00;

    for (int k0 = 0; k0 < K; k0 += BK) {
        {
            int grow = brow + sRow;
            float vals[8];
            if (grow < M) {
                const float* p = A + (size_t)grow * K + k0 + sKb;
                float4 v0 = ((const float4*)p)[0];
                float4 v1 = ((const float4*)p)[1];
                vals[0] = v0.x; vals[1] = v0.y; vals[2] = v0.z; vals[3] = v0.w;
                vals[4] = v1.x; vals[5] = v1.y; vals[6] = v1.z; vals[7] = v1.w;
            } else {
                #pragma unroll
                for (int i = 0; i < 8; i++) vals[i] = 0.f;
            }
            u16x8 w;
            #pragma unroll
            for (int i = 0; i < 8; i++) w[i] = f2bf(vals[i]);
            *(u16x8*)&As[sRow][sKb] = w;
        }
        {
            const u16x8* p = (const u16x8*)(Bt + (size_t)(bcol + sRow) * K + k0 + sKb);
            *(u16x8*)&Bs[sRow][sKb] = *p;
        }
        __syncthreads();
        bf16x8 a0 = *(const bf16x8*)&As[wr * 32 + lr][lq * 8];
        bf16x8 a1 = *(const bf16x8*)&As[wr * 32 + 16 + lr][lq * 8];
        bf16x8 b0 = *(const bf16x8*)&Bs[wc * 32 + lr][lq * 8];
        bf16x8 b1 = *(const bf16x8*)&Bs[wc * 32 + 16 + lr][lq * 8];
        acc00 = __builtin_amdgcn_mfma_f32_16x16x32_bf16(a0, b0, acc00, 0, 0, 0);
        acc01 = __builtin_amdgcn_mfma_f32_16x16x32_bf16(a0, b1, acc01, 0, 0, 0);
        acc10 = __builtin_amdgcn_mfma_f32_16x16x32_bf16(a1, b0, acc10, 0, 0, 0);
        acc11 = __builtin_amdgcn_mfma_f32_16x16x32_bf16(a1, b1, acc11, 0, 0, 0);
        __syncthreads();
    }
    f32x4 accs[2][2] = {{acc00, acc01}, {acc10, acc11}};
    #pragma unroll
    for (int rm = 0; rm < 2; rm++) {
        #pragma unroll
        for (int cn = 0; cn < 2; cn++) {
            int row = brow + wr * 32 + rm * 16 + lq * 4;
            int col = bcol + wc * 32 + cn * 16 + lr;
            #pragma unroll
            for (int r = 0; r < 4; r++) {
                if (row + r >= M) continue;
                float v = accs[rm][cn][r];
                if (MODE == 2) {
                    ((unsigned short*)Cv)[(size_t)(row + r) * Ncols + col] = f2bf(v);
                } else {
                    v += bias[col];
                    if (MODE == 1) v += addin[(size_t)(row + r) * Ncols + col];
                    if (MODE == 3) {
                        if (col < 768) ((float*)Cv)[(size_t)(row + r) * 768 + col] = v;
                        else           C2[(size_t)(row + r) * 256 + (col - 768)] = v;
                    } else {
                        ((float*)Cv)[(size_t)(row + r) * Ncols + col] = v;
                    }
                }
            }
        }
    }
}

// ---------------- RGCN aggregate: gather, one wave per dst node ----------------
__global__ __launch_bounds__(256) void k_rgcn(const unsigned short* __restrict__ Yall, const int* __restrict__ csr,
                                              const int* __restrict__ start, const int* __restrict__ deg,
                                              const float* __restrict__ inv, float* __restrict__ agg) {
    int node = blockIdx.x * 4 + (threadIdx.x >> 6);
    int lane = threadIdx.x & 63;
    if (node >= NNODES) return;
    int s0 = start[node], n = deg[node];
    float4 acc = make_float4(0.f, 0.f, 0.f, 0.f);
    for (int j = 0; j < n; j++) {
        int pk = csr[s0 + j];
        int s = pk >> 3, r = pk & 7;
        float sc = inv[node * RREL + r];
        ushort4 y = *(const ushort4*)(Yall + (size_t)s * 2048 + r * 256 + lane * 4);
        acc.x += sc * bf2f(y.x);
        acc.y += sc * bf2f(y.y);
        acc.z += sc * bf2f(y.z);
        acc.w += sc * bf2f(y.w);
    }
    ((float4*)(agg + (size_t)node * 256))[lane] = acc;
}

// ---------------- fused attention: one wave per dst node, online softmax ----------------
__global__ __launch_bounds__(256) void k_attn(const float* __restrict__ QKV, const int* __restrict__ csr,
                                              const int* __restrict__ start, const int* __restrict__ deg,
                                              float* __restrict__ out) {
    int node = blockIdx.x * 4 + (threadIdx.x >> 6);
    int lane = threadIdx.x & 63;
    if (node >= NNODES) return;
    int s0 = start[node], n = deg[node];
    if (n == 0) return;  // out row keeps skip value
    float4 q = ((const float4*)(QKV + (size_t)node * 768))[lane];
    float m = -INFINITY, den = 0.f;
    float4 acc = make_float4(0.f, 0.f, 0.f, 0.f);
    for (int j = 0; j < n; j++) {
        int s = csr[s0 + j] >> 3;
        float4 kk = ((const float4*)(QKV + (size_t)s * 768 + 256))[lane];
        float4 vv = ((const float4*)(QKV + (size_t)s * 768 + 512))[lane];
        float p = q.x * kk.x + q.y * kk.y + q.z * kk.z + q.w * kk.w;
        #pragma unroll
        for (int o = 32; o; o >>= 1) p += __shfl_xor(p, o);
        p *= 0.0625f;
        if (p > m) {
            float r = __expf(m - p);  // first iter: exp(-inf)=0
            den *= r;
            acc.x *= r; acc.y *= r; acc.z *= r; acc.w *= r;
            m = p;
        }
        float ex = __expf(p - m);
        den += ex;
        acc.x += ex * vv.x; acc.y += ex * vv.y; acc.z += ex * vv.z; acc.w += ex * vv.w;
    }
    float rinv = 1.0f / fmaxf(den, 1e-16f);
    float4* o4 = (float4*)(out + (size_t)node * 256);
    float4 o = o4[lane];
    o.x += acc.x * rinv; o.y += acc.y * rinv; o.z += acc.z * rinv; o.w += acc.w * rinv;
    o4[lane] = o;
}

// ---------------- batch norm + leaky relu ----------------
__global__ __launch_bounds__(256) void k_bnstats(const float* __restrict__ out, float* __restrict__ sums,
                                                 float* __restrict__ sumsq) {
    int c = threadIdx.x;
    int rows_per = (NNODES + gridDim.x - 1) / gridDim.x;
    int r0 = blockIdx.x * rows_per;
    int r1 = r0 + rows_per; if (r1 > NNODES) r1 = NNODES;
    float s = 0.f, ss = 0.f;
    for (int r = r0; r < r1; r++) {
        float v = out[(size_t)r * 256 + c];
        s += v; ss += v * v;
    }
    atomicAdd(&sums[c], s);
    atomicAdd(&sumsq[c], ss);
}

__global__ __launch_bounds__(256) void k_bnfinal(const float* __restrict__ sums, const float* __restrict__ sumsq,
                                                 const float* __restrict__ gamma, const float* __restrict__ beta,
                                                 float* __restrict__ scale, float* __restrict__ shift) {
    int c = threadIdx.x;
    float mu = sums[c] * (1.0f / NNODES);
    float var = sumsq[c] * (1.0f / NNODES) - mu * mu;
    float sc = gamma[c] * rsqrtf(fmaxf(var, 0.f) + EPSBN);
    scale[c] = sc;
    shift[c] = beta[c] - mu * sc;
}

__global__ __launch_bounds__(256) void k_bnapply(float4* __restrict__ out, const float* __restrict__ scale,
                                                 const float* __restrict__ shift) {
    int i = blockIdx.x * 256 + threadIdx.x;
    if (i >= NNODES * 64) return;
    int c4 = i & 63;
    float4 v = out[i];
    float4 s4 = ((const float4*)scale)[c4];
    float4 h4 = ((const float4*)shift)[c4];
    v.x = v.x * s4.x + h4.x; v.y = v.y * s4.y + h4.y;
    v.z = v.z * s4.z + h4.z; v.w = v.w * s4.w + h4.w;
    v.x = v.x > 0.f ? v.x : 0.01f * v.x;
    v.y = v.y > 0.f ? v.y : 0.01f * v.y;
    v.z = v.z > 0.f ? v.z : 0.01f * v.z;
    v.w = v.w > 0.f ? v.w : 0.01f * v.w;
    out[i] = v;
}

extern "C" void kernel_launch(void* const* d_in, const int* in_sizes, int n_in,
                              void* d_out, int out_size, void* d_ws, size_t ws_size,
                              hipStream_t stream) {
    const float* x = (const float*)d_in[0];
    const int* ei = (const int*)d_in[1];
    const int* etype = (const int*)d_in[2];
    const float* Wrel = (const float*)d_in[3];
    const float* Wroot = (const float*)d_in[4];
    const float* b1 = (const float*)d_in[5];
    const float* Wq = (const float*)d_in[6];
    const float* bq = (const float*)d_in[7];
    const float* Wk = (const float*)d_in[8];
    const float* bk = (const float*)d_in[9];
    const float* Wv = (const float*)d_in[10];
    const float* bv = (const float*)d_in[11];
    const float* Ws = (const float*)d_in[12];
    const float* bs = (const float*)d_in[13];
    const float* gamma = (const float*)d_in[14];
    const float* beta = (const float*)d_in[15];
    float* out = (float*)d_out;

    const int* srcA = ei;
    const int* dstA = ei + NEDGES;

    // ---- workspace layout ----
    char* w = (char*)d_ws;
    unsigned short* Yall = (unsigned short*)w;  w += (size_t)NNODES * 2048 * 2;  // 81.92 MB
    float* agg = (float*)w;                     w += (size_t)NNODES * 256 * 4;   // 20.48 MB
    float* QKV = (float*)w;                     w += (size_t)NNODES * 768 * 4;   // 61.44 MB
    unsigned short* Brel = (unsigned short*)w;  w += (size_t)2048 * 256 * 2;
    unsigned short* Broot = (unsigned short*)w; w += (size_t)256 * 256 * 2;
    unsigned short* B2t = (unsigned short*)w;   w += (size_t)1024 * 256 * 2;
    float* bias2 = (float*)w;                   w += 1024 * 4;
    int* cnt = (int*)w;                         w += (size_t)NNODES * RREL * 4;
    float* invc = (float*)w;                    w += (size_t)NNODES * RREL * 4;
    int* deg = (int*)w;                         w += (size_t)NNODES * 4;
    int* startv = (int*)w;                      w += (size_t)NNODES * 4;
    int* cursor = (int*)w;                      w += (size_t)NNODES * 4;
    int* csr = (int*)w;                         w += (size_t)NEDGES * 4;
    float* sums = (float*)w;                    w += 1024;
    float* sumsq = (float*)w;                   w += 1024;
    float* scale = (float*)w;                   w += 1024;
    float* shift = (float*)w;                   w += 1024;
    size_t need = (size_t)(w - (char*)d_ws);
    if (ws_size < need) return;

    hipMemsetAsync(cnt, 0, (size_t)NNODES * RREL * 4, stream);
    hipMemsetAsync(sums, 0, 1024, stream);
    hipMemsetAsync(sumsq, 0, 1024, stream);

    // CSR build
    k_count<<<(NEDGES + 255) / 256, 256, 0, stream>>>(dstA, etype, cnt);
    k_inv<<<(NNODES * RREL + 255) / 256, 256, 0, stream>>>(cnt, invc);
    k_degsum<<<(NNODES + 255) / 256, 256, 0, stream>>>(cnt, deg);
    k_scan<<<1, 256, 0, stream>>>(deg, startv, cursor);
    k_fill<<<(NEDGES + 255) / 256, 256, 0, stream>>>(srcA, dstA, etype, cursor, csr);

    // weight prep
    k_prepBrel<<<(2048 * 256 + 255) / 256, 256, 0, stream>>>(Wrel, Brel);
    k_prepBroot<<<(256 * 256 + 255) / 256, 256, 0, stream>>>(Wroot, Broot);
    k_prepB2<<<(1024 * 256 + 255) / 256, 256, 0, stream>>>(Wq, Wk, Wv, Ws, bq, bk, bv, bs, B2t, bias2);

    // Yall[N,2048] (bf16) = x @ [W_0|...|W_7]
    dim3 gA((NNODES + BM - 1) / BM, 2048 / BN);
    k_gemm<2><<<gA, 256, 0, stream>>>(x, Brel, nullptr, nullptr, (void*)Yall, nullptr, NNODES, 256, 2048);

    // agg[dst] = sum_r inv * Yall[src, r]  (gather, no atomics)
    k_rgcn<<<(NNODES + 3) / 4, 256, 0, stream>>>(Yall, csr, startv, deg, invc, agg);

    // x1 = x @ W_root + b1 + agg  (in place over agg)
    dim3 gB((NNODES + BM - 1) / BM, 256 / BN);
    k_gemm<1><<<gB, 256, 0, stream>>>(x, Broot, b1, agg, (void*)agg, nullptr, NNODES, 256, 256);
    float* x1 = agg;

    // [q|k|v -> QKV, skip -> out] = x1 @ [Wq|Wk|Wv|Wskip] + bias2
    dim3 gC((NNODES + BM - 1) / BM, 1024 / BN);
    k_gemm<3><<<gC, 256, 0, stream>>>(x1, B2t, bias2, nullptr, (void*)QKV, out, NNODES, 256, 1024);

    // fused attention (gather, online softmax, no atomics)
    k_attn<<<(NNODES + 3) / 4, 256, 0, stream>>>(QKV, csr, startv, deg, out);

    k_bnstats<<<200, 256, 0, stream>>>(out, sums, sumsq);
    k_bnfinal<<<1, 256, 0, stream>>>(sums, sumsq, gamma, beta, scale, shift);
    k_bnapply<<<(NNODES * 64 + 255) / 256, 256, 0, stream>>>((float4*)out, scale, shift);
}

// Round 4
// 389.439 us; speedup vs baseline: 6.3998x; 1.2045x over previous
//
#include <hip/hip_runtime.h>
#include <math.h>

#define NNODES 20000
#define NEDGES 320000
#define RREL 8
#define EPSBN 1e-5f

typedef float f32x4 __attribute__((ext_vector_type(4)));
typedef __bf16 bf16x8 __attribute__((ext_vector_type(8)));
typedef unsigned short u16x8 __attribute__((ext_vector_type(8)));

static __device__ __forceinline__ unsigned short f2bf(float f) {
    unsigned int x = __builtin_bit_cast(unsigned int, f);
    unsigned int r = x + 0x7FFFu + ((x >> 16) & 1u);
    return (unsigned short)(r >> 16);
}
static __device__ __forceinline__ float bf2f(unsigned short u) {
    unsigned int x = ((unsigned int)u) << 16;
    return __builtin_bit_cast(float, x);
}

// ---------------- degree count / inverse / CSR ----------------
__global__ __launch_bounds__(256) void k_count(const int* __restrict__ dst, const int* __restrict__ et,
                                               int* __restrict__ cnt) {
    int e = blockIdx.x * 256 + threadIdx.x;
    if (e >= NEDGES) return;
    atomicAdd(&cnt[dst[e] * RREL + et[e]], 1);
}

__global__ __launch_bounds__(256) void k_inv(const int* __restrict__ cnt, float* __restrict__ inv) {
    int i = blockIdx.x * 256 + threadIdx.x;
    if (i >= NNODES * RREL) return;
    int c = cnt[i];
    inv[i] = 1.0f / (float)(c > 0 ? c : 1);
}

__global__ __launch_bounds__(256) void k_degsum(const int* __restrict__ cnt, int* __restrict__ deg) {
    int i = blockIdx.x * 256 + threadIdx.x;
    if (i >= NNODES) return;
    const int4* p = (const int4*)(cnt + i * 8);
    int4 a = p[0], b = p[1];
    deg[i] = a.x + a.y + a.z + a.w + b.x + b.y + b.z + b.w;
}

__global__ __launch_bounds__(256) void k_scan(const int* __restrict__ deg, int* __restrict__ start,
                                              int* __restrict__ cursor) {
    __shared__ int part[256];
    int t = threadIdx.x;
    const int chunk = (NNODES + 255) / 256;
    int i0 = t * chunk, i1 = i0 + chunk;
    if (i1 > NNODES) i1 = NNODES;
    int s = 0;
    for (int i = i0; i < i1; i++) s += deg[i];
    part[t] = s;
    __syncthreads();
    if (t == 0) {
        int acc = 0;
        for (int j = 0; j < 256; j++) { int v = part[j]; part[j] = acc; acc += v; }
    }
    __syncthreads();
    int acc = part[t];
    for (int i = i0; i < i1; i++) { start[i] = acc; cursor[i] = acc; acc += deg[i]; }
}

__global__ __launch_bounds__(256) void k_fill(const int* __restrict__ src, const int* __restrict__ dst,
                                              const int* __restrict__ et, int* __restrict__ cursor,
                                              int* __restrict__ csr) {
    int e = blockIdx.x * 256 + threadIdx.x;
    if (e >= NEDGES) return;
    int pos = atomicAdd(&cursor[dst[e]], 1);
    csr[pos] = src[e] * 8 + et[e];
}

// ---------------- x -> bf16 ----------------
__global__ __launch_bounds__(256) void k_tobf(const float* __restrict__ x, unsigned short* __restrict__ xb) {
    int i = blockIdx.x * 256 + threadIdx.x;   // one per 8 elems
    if (i >= NNODES * 32) return;
    const float4* p = (const float4*)(x + (size_t)i * 8);
    float4 v0 = p[0], v1 = p[1];
    u16x8 w;
    w[0] = f2bf(v0.x); w[1] = f2bf(v0.y); w[2] = f2bf(v0.z); w[3] = f2bf(v0.w);
    w[4] = f2bf(v1.x); w[5] = f2bf(v1.y); w[6] = f2bf(v1.z); w[7] = f2bf(v1.w);
    *(u16x8*)(xb + (size_t)i * 8) = w;
}

// ---------------- weight prep (transpose + bf16) ----------------
__global__ __launch_bounds__(256) void k_prepBrel(const float* __restrict__ Wrel, unsigned short* __restrict__ B) {
    int idx = blockIdx.x * 256 + threadIdx.x;
    if (idx >= 2048 * 256) return;
    int col = idx >> 8, g = idx & 255;
    int r = col >> 8, h = col & 255;
    B[idx] = f2bf(Wrel[(size_t)r * 65536 + (size_t)g * 256 + h]);
}

__global__ __launch_bounds__(256) void k_prepBroot(const float* __restrict__ Wroot, unsigned short* __restrict__ B) {
    int idx = blockIdx.x * 256 + threadIdx.x;
    if (idx >= 256 * 256) return;
    int h = idx >> 8, g = idx & 255;
    B[idx] = f2bf(Wroot[(size_t)g * 256 + h]);
}

__global__ __launch_bounds__(256) void k_prepB2(const float* __restrict__ Wq, const float* __restrict__ Wk,
                                                const float* __restrict__ Wv, const float* __restrict__ Ws,
                                                const float* __restrict__ bq, const float* __restrict__ bk,
                                                const float* __restrict__ bv, const float* __restrict__ bs,
                                                unsigned short* __restrict__ B2t, float* __restrict__ bias2) {
    int idx = blockIdx.x * 256 + threadIdx.x;
    if (idx >= 1024 * 256) return;
    int c = idx / 256, g = idx % 256;
    const float* W = (c < 256) ? Wq : (c < 512) ? Wk : (c < 768) ? Wv : Ws;
    int cc = c & 255;
    B2t[idx] = f2bf(W[(size_t)g * 256 + cc]);
    if (g == 0) {
        const float* B = (c < 256) ? bq : (c < 512) ? bk : (c < 768) ? bv : bs;
        bias2[c] = B[cc];
    }
}

// ---------------- bf16 MFMA GEMM, A resident in LDS ----------------
// A[M,256] bf16; Bt[Ncols,256] bf16 (row-major, pre-transposed).
// Block: 64 rows, loops cpb cols in BN=128 tiles. 4 waves, each 32x64 out.
// MODE 1: bf16 out = acc + bias + addin(f32)   (root GEMM -> x1_bf)
// MODE 2: bf16 out = acc                        (Yall)
// MODE 3: col<768 -> bf16 QKV[row*768+col]=acc+bias; col>=768 -> f32 C2[row*256+col-768]=acc+bias
template<int MODE>
__global__ __launch_bounds__(256) void k_gemm2(const unsigned short* __restrict__ A,
                                               const unsigned short* __restrict__ Bt,
                                               const float* __restrict__ bias, const float* __restrict__ addin,
                                               void* __restrict__ Cv, float* __restrict__ C2,
                                               int M, int Ncols, int cpb) {
    __shared__ unsigned short As[64][264];   // 33.8 KB, stride 528B -> conflict-benign reads
    __shared__ unsigned short Bs[128][40];   // 10.2 KB
    int tid = threadIdx.x;
    int lane = tid & 63, wid = tid >> 6;
    int wr = wid >> 1, wc = wid & 1;
    int lr = lane & 15, lq = lane >> 4;
    int brow = blockIdx.x * 64;
    int colBeg = blockIdx.y * cpb;

    // stage full A tile (64 x 256) once
    {
        int row = tid >> 2;
        int cb = (tid & 3) * 64;
        int grow = brow + row;
        #pragma unroll
        for (int j = 0; j < 8; j++) {
            u16x8 v = {0, 0, 0, 0, 0, 0, 0, 0};
            if (grow < M) v = *(const u16x8*)(A + (size_t)grow * 256 + cb + j * 8);
            *(u16x8*)&As[row][cb + j * 8] = v;
        }
    }

    for (int bc = 0; bc < cpb; bc += 128) {
        int bcol = colBeg + bc;
        f32x4 acc[2][4];
        #pragma unroll
        for (int i = 0; i < 2; i++)
            #pragma unroll
            for (int j = 0; j < 4; j++) acc[i][j] = (f32x4){0.f, 0.f, 0.f, 0.f};

        for (int k0 = 0; k0 < 256; k0 += 32) {
            __syncthreads();   // prior reads (or A-stage on first pass) done before B overwrite
            {
                int r = tid >> 1, h = (tid & 1) * 16;
                const u16x8* p = (const u16x8*)(Bt + (size_t)(bcol + r) * 256 + k0 + h);
                *(u16x8*)&Bs[r][h] = p[0];
                *(u16x8*)&Bs[r][h + 8] = p[1];
            }
            __syncthreads();
            bf16x8 a0 = *(const bf16x8*)&As[wr * 32 + lr][k0 + lq * 8];
            bf16x8 a1 = *(const bf16x8*)&As[wr * 32 + 16 + lr][k0 + lq * 8];
            bf16x8 b0 = *(const bf16x8*)&Bs[wc * 64 + lr][lq * 8];
            bf16x8 b1 = *(const bf16x8*)&Bs[wc * 64 + 16 + lr][lq * 8];
            bf16x8 b2 = *(const bf16x8*)&Bs[wc * 64 + 32 + lr][lq * 8];
            bf16x8 b3 = *(const bf16x8*)&Bs[wc * 64 + 48 + lr][lq * 8];
            acc[0][0] = __builtin_amdgcn_mfma_f32_16x16x32_bf16(a0, b0, acc[0][0], 0, 0, 0);
            acc[0][1] = __builtin_amdgcn_mfma_f32_16x16x32_bf16(a0, b1, acc[0][1], 0, 0, 0);
            acc[0][2] = __builtin_amdgcn_mfma_f32_16x16x32_bf16(a0, b2, acc[0][2], 0, 0, 0);
            acc[0][3] = __builtin_amdgcn_mfma_f32_16x16x32_bf16(a0, b3, acc[0][3], 0, 0, 0);
            acc[1][0] = __builtin_amdgcn_mfma_f32_16x16x32_bf16(a1, b0, acc[1][0], 0, 0, 0);
            acc[1][1] = __builtin_amdgcn_mfma_f32_16x16x32_bf16(a1, b1, acc[1][1], 0, 0, 0);
            acc[1][2] = __builtin_amdgcn_mfma_f32_16x16x32_bf16(a1, b2, acc[1][2], 0, 0, 0);
            acc[1][3] = __builtin_amdgcn_mfma_f32_16x16x32_bf16(a1, b3, acc[1][3], 0, 0, 0);
        }

        // epilogue: C/D layout col=lane&15, row=(lane>>4)*4+reg
        #pragma unroll
        for (int rm = 0; rm < 2; rm++) {
            #pragma unroll
            for (int cn = 0; cn < 4; cn++) {
                int row = brow + wr * 32 + rm * 16 + lq * 4;
                int col = bcol + wc * 64 + cn * 16 + lr;
                #pragma unroll
                for (int r = 0; r < 4; r++) {
                    int gr = row + r;
                    if (gr >= M) continue;
                    float v = acc[rm][cn][r];
                    if (MODE == 2) {
                        ((unsigned short*)Cv)[(size_t)gr * Ncols + col] = f2bf(v);
                    } else if (MODE == 1) {
                        v += bias[col] + addin[(size_t)gr * 256 + col];
                        ((unsigned short*)Cv)[(size_t)gr * 256 + col] = f2bf(v);
                    } else {  // MODE 3
                        v += bias[col];
                        if (col < 768) ((unsigned short*)Cv)[(size_t)gr * 768 + col] = f2bf(v);
                        else           C2[(size_t)gr * 256 + (col - 768)] = v;
                    }
                }
            }
        }
    }
}

// ---------------- RGCN aggregate: gather, one wave per dst node ----------------
__global__ __launch_bounds__(256) void k_rgcn(const unsigned short* __restrict__ Yall, const int* __restrict__ csr,
                                              const int* __restrict__ start, const int* __restrict__ deg,
                                              const float* __restrict__ inv, float* __restrict__ agg) {
    int node = blockIdx.x * 4 + (threadIdx.x >> 6);
    int lane = threadIdx.x & 63;
    if (node >= NNODES) return;
    int s0 = start[node], n = deg[node];
    float4 acc = make_float4(0.f, 0.f, 0.f, 0.f);
    for (int j = 0; j < n; j++) {
        int pk = csr[s0 + j];
        int s = pk >> 3, r = pk & 7;
        float sc = inv[node * RREL + r];
        ushort4 y = *(const ushort4*)(Yall + (size_t)s * 2048 + r * 256 + lane * 4);
        acc.x += sc * bf2f(y.x);
        acc.y += sc * bf2f(y.y);
        acc.z += sc * bf2f(y.z);
        acc.w += sc * bf2f(y.w);
    }
    ((float4*)(agg + (size_t)node * 256))[lane] = acc;
}

// ---------------- fused attention (bf16 QKV): one wave per node, online softmax ----------------
__global__ __launch_bounds__(256) void k_attn(const unsigned short* __restrict__ QKV, const int* __restrict__ csr,
                                              const int* __restrict__ start, const int* __restrict__ deg,
                                              float* __restrict__ out) {
    int node = blockIdx.x * 4 + (threadIdx.x >> 6);
    int lane = threadIdx.x & 63;
    if (node >= NNODES) return;
    int s0 = start[node], n = deg[node];
    if (n == 0) return;  // out row keeps skip value
    ushort4 qu = *(const ushort4*)(QKV + (size_t)node * 768 + lane * 4);
    float q0 = bf2f(qu.x), q1 = bf2f(qu.y), q2 = bf2f(qu.z), q3 = bf2f(qu.w);
    float m = -INFINITY, den = 0.f;
    float4 acc = make_float4(0.f, 0.f, 0.f, 0.f);
    for (int j = 0; j < n; j++) {
        int s = csr[s0 + j] >> 3;
        const unsigned short* base = QKV + (size_t)s * 768;
        ushort4 ku = *(const ushort4*)(base + 256 + lane * 4);
        ushort4 vu = *(const ushort4*)(base + 512 + lane * 4);
        float p = q0 * bf2f(ku.x) + q1 * bf2f(ku.y) + q2 * bf2f(ku.z) + q3 * bf2f(ku.w);
        #pragma unroll
        for (int o = 32; o; o >>= 1) p += __shfl_xor(p, o);
        p *= 0.0625f;
        if (p > m) {
            float rr = __expf(m - p);   // first iter: exp(-inf)=0
            den *= rr;
            acc.x *= rr; acc.y *= rr; acc.z *= rr; acc.w *= rr;
            m = p;
        }
        float ex = __expf(p - m);
        den += ex;
        acc.x += ex * bf2f(vu.x); acc.y += ex * bf2f(vu.y);
        acc.z += ex * bf2f(vu.z); acc.w += ex * bf2f(vu.w);
    }
    float rinv = 1.0f / fmaxf(den, 1e-16f);
    float4* o4 = (float4*)(out + (size_t)node * 256);
    float4 o = o4[lane];
    o.x += acc.x * rinv; o.y += acc.y * rinv; o.z += acc.z * rinv; o.w += acc.w * rinv;
    o4[lane] = o;
}

// ---------------- batch norm + leaky relu ----------------
__global__ __launch_bounds__(256) void k_bnstats(const float* __restrict__ out, float* __restrict__ sums,
                                                 float* __restrict__ sumsq) {
    int c = threadIdx.x;
    int rows_per = (NNODES + gridDim.x - 1) / gridDim.x;
    int r0 = blockIdx.x * rows_per;
    int r1 = r0 + rows_per; if (r1 > NNODES) r1 = NNODES;
    float s = 0.f, ss = 0.f;
    for (int r = r0; r < r1; r++) {
        float v = out[(size_t)r * 256 + c];
        s += v; ss += v * v;
    }
    atomicAdd(&sums[c], s);
    atomicAdd(&sumsq[c], ss);
}

__global__ __launch_bounds__(256) void k_bnfinal(const float* __restrict__ sums, const float* __restrict__ sumsq,
                                                 const float* __restrict__ gamma, const float* __restrict__ beta,
                                                 float* __restrict__ scale, float* __restrict__ shift) {
    int c = threadIdx.x;
    float mu = sums[c] * (1.0f / NNODES);
    float var = sumsq[c] * (1.0f / NNODES) - mu * mu;
    float sc = gamma[c] * rsqrtf(fmaxf(var, 0.f) + EPSBN);
    scale[c] = sc;
    shift[c] = beta[c] - mu * sc;
}

__global__ __launch_bounds__(256) void k_bnapply(float4* __restrict__ out, const float* __restrict__ scale,
                                                 const float* __restrict__ shift) {
    int i = blockIdx.x * 256 + threadIdx.x;
    if (i >= NNODES * 64) return;
    int c4 = i & 63;
    float4 v = out[i];
    float4 s4 = ((const float4*)scale)[c4];
    float4 h4 = ((const float4*)shift)[c4];
    v.x = v.x * s4.x + h4.x; v.y = v.y * s4.y + h4.y;
    v.z = v.z * s4.z + h4.z; v.w = v.w * s4.w + h4.w;
    v.x = v.x > 0.f ? v.x : 0.01f * v.x;
    v.y = v.y > 0.f ? v.y : 0.01f * v.y;
    v.z = v.z > 0.f ? v.z : 0.01f * v.z;
    v.w = v.w > 0.f ? v.w : 0.01f * v.w;
    out[i] = v;
}

extern "C" void kernel_launch(void* const* d_in, const int* in_sizes, int n_in,
                              void* d_out, int out_size, void* d_ws, size_t ws_size,
                              hipStream_t stream) {
    const float* x = (const float*)d_in[0];
    const int* ei = (const int*)d_in[1];
    const int* etype = (const int*)d_in[2];
    const float* Wrel = (const float*)d_in[3];
    const float* Wroot = (const float*)d_in[4];
    const float* b1 = (const float*)d_in[5];
    const float* Wq = (const float*)d_in[6];
    const float* bq = (const float*)d_in[7];
    const float* Wk = (const float*)d_in[8];
    const float* bk = (const float*)d_in[9];
    const float* Wv = (const float*)d_in[10];
    const float* bv = (const float*)d_in[11];
    const float* Ws = (const float*)d_in[12];
    const float* bs = (const float*)d_in[13];
    const float* gamma = (const float*)d_in[14];
    const float* beta = (const float*)d_in[15];
    float* out = (float*)d_out;

    const int* srcA = ei;
    const int* dstA = ei + NEDGES;

    // ---- workspace layout ----
    char* w = (char*)d_ws;
    unsigned short* Yall = (unsigned short*)w;  w += (size_t)NNODES * 2048 * 2;  // 81.9 MB
    unsigned short* x_bf = (unsigned short*)w;  w += (size_t)NNODES * 256 * 2;   // 10.2 MB
    unsigned short* x1bf = (unsigned short*)w;  w += (size_t)NNODES * 256 * 2;   // 10.2 MB
    float* agg = (float*)w;                     w += (size_t)NNODES * 256 * 4;   // 20.5 MB
    unsigned short* QKVbf = (unsigned short*)w; w += (size_t)NNODES * 768 * 2;   // 30.7 MB
    unsigned short* Brel = (unsigned short*)w;  w += (size_t)2048 * 256 * 2;
    unsigned short* Broot = (unsigned short*)w; w += (size_t)256 * 256 * 2;
    unsigned short* B2t = (unsigned short*)w;   w += (size_t)1024 * 256 * 2;
    float* bias2 = (float*)w;                   w += 1024 * 4;
    int* cnt = (int*)w;                         w += (size_t)NNODES * RREL * 4;
    float* invc = (float*)w;                    w += (size_t)NNODES * RREL * 4;
    int* deg = (int*)w;                         w += (size_t)NNODES * 4;
    int* startv = (int*)w;                      w += (size_t)NNODES * 4;
    int* cursor = (int*)w;                      w += (size_t)NNODES * 4;
    int* csr = (int*)w;                         w += (size_t)NEDGES * 4;
    float* sums = (float*)w;                    w += 1024;
    float* sumsq = (float*)w;                   w += 1024;
    float* scale = (float*)w;                   w += 1024;
    float* shift = (float*)w;                   w += 1024;
    size_t need = (size_t)(w - (char*)d_ws);
    if (ws_size < need) return;

    hipMemsetAsync(cnt, 0, (size_t)NNODES * RREL * 4, stream);
    hipMemsetAsync(sums, 0, 1024, stream);
    hipMemsetAsync(sumsq, 0, 1024, stream);

    // CSR build
    k_count<<<(NEDGES + 255) / 256, 256, 0, stream>>>(dstA, etype, cnt);
    k_inv<<<(NNODES * RREL + 255) / 256, 256, 0, stream>>>(cnt, invc);
    k_degsum<<<(NNODES + 255) / 256, 256, 0, stream>>>(cnt, deg);
    k_scan<<<1, 256, 0, stream>>>(deg, startv, cursor);
    k_fill<<<(NEDGES + 255) / 256, 256, 0, stream>>>(srcA, dstA, etype, cursor, csr);

    // prep: x->bf16, weights transpose+bf16
    k_tobf<<<(NNODES * 32 + 255) / 256, 256, 0, stream>>>(x, x_bf);
    k_prepBrel<<<(2048 * 256 + 255) / 256, 256, 0, stream>>>(Wrel, Brel);
    k_prepBroot<<<(256 * 256 + 255) / 256, 256, 0, stream>>>(Wroot, Broot);
    k_prepB2<<<(1024 * 256 + 255) / 256, 256, 0, stream>>>(Wq, Wk, Wv, Ws, bq, bk, bv, bs, B2t, bias2);

    // Yall[N,2048] bf16 = x @ [W_0|...|W_7]
    k_gemm2<2><<<dim3(313, 4), 256, 0, stream>>>(x_bf, Brel, nullptr, nullptr, (void*)Yall, nullptr,
                                                 NNODES, 2048, 512);

    // agg[dst] = sum_r inv * Yall[src, r]
    k_rgcn<<<(NNODES + 3) / 4, 256, 0, stream>>>(Yall, csr, startv, deg, invc, agg);

    // x1_bf = bf16(x @ W_root + b1 + agg)
    k_gemm2<1><<<dim3(313, 2), 256, 0, stream>>>(x_bf, Broot, b1, agg, (void*)x1bf, nullptr,
                                                 NNODES, 256, 128);

    // [q|k|v -> QKVbf (bf16), skip -> out (f32)] = x1 @ [Wq|Wk|Wv|Wskip] + bias2
    k_gemm2<3><<<dim3(313, 4), 256, 0, stream>>>(x1bf, B2t, bias2, nullptr, (void*)QKVbf, out,
                                                 NNODES, 1024, 256);

    // fused attention (gather, online softmax)
    k_attn<<<(NNODES + 3) / 4, 256, 0, stream>>>(QKVbf, csr, startv, deg, out);

    k_bnstats<<<200, 256, 0, stream>>>(out, sums, sumsq);
    k_bnfinal<<<1, 256, 0, stream>>>(sums, sumsq, gamma, beta, scale, shift);
    k_bnapply<<<(NNODES * 64 + 255) / 256, 256, 0, stream>>>((float4*)out, scale, shift);
}

// Round 5
// 347.504 us; speedup vs baseline: 7.1721x; 1.1207x over previous
//
#include <hip/hip_runtime.h>
#include <math.h>

#define NNODES 20000
#define NEDGES 320000
#define RREL 8
#define EPSBN 1e-5f

typedef float f32x4 __attribute__((ext_vector_type(4)));
typedef __bf16 bf16x8 __attribute__((ext_vector_type(8)));
typedef unsigned short u16x8 __attribute__((ext_vector_type(8)));

static __device__ __forceinline__ unsigned short f2bf(float f) {
    unsigned int x = __builtin_bit_cast(unsigned int, f);
    unsigned int r = x + 0x7FFFu + ((x >> 16) & 1u);
    return (unsigned short)(r >> 16);
}
static __device__ __forceinline__ float bf2f(unsigned short u) {
    unsigned int x = ((unsigned int)u) << 16;
    return __builtin_bit_cast(float, x);
}

// ---------------- CSR build ----------------
__global__ __launch_bounds__(256) void k_count(const int* __restrict__ dst, const int* __restrict__ et,
                                               int* __restrict__ cnt) {
    int e = blockIdx.x * 256 + threadIdx.x;
    if (e >= NEDGES) return;
    atomicAdd(&cnt[dst[e] * RREL + et[e]], 1);
}

// per node: inv[8] and deg
__global__ __launch_bounds__(256) void k_invdeg(const int* __restrict__ cnt, float* __restrict__ inv,
                                                int* __restrict__ deg) {
    int i = blockIdx.x * 256 + threadIdx.x;
    if (i >= NNODES) return;
    const int4* p = (const int4*)(cnt + i * 8);
    int4 a = p[0], b = p[1];
    deg[i] = a.x + a.y + a.z + a.w + b.x + b.y + b.z + b.w;
    float4 i0, i1;
    i0.x = 1.0f / (float)(a.x > 0 ? a.x : 1);
    i0.y = 1.0f / (float)(a.y > 0 ? a.y : 1);
    i0.z = 1.0f / (float)(a.z > 0 ? a.z : 1);
    i0.w = 1.0f / (float)(a.w > 0 ? a.w : 1);
    i1.x = 1.0f / (float)(b.x > 0 ? b.x : 1);
    i1.y = 1.0f / (float)(b.y > 0 ? b.y : 1);
    i1.z = 1.0f / (float)(b.z > 0 ? b.z : 1);
    i1.w = 1.0f / (float)(b.w > 0 ? b.w : 1);
    ((float4*)(inv + i * 8))[0] = i0;
    ((float4*)(inv + i * 8))[1] = i1;
}

__global__ __launch_bounds__(256) void k_scan(const int* __restrict__ deg, int* __restrict__ start,
                                              int* __restrict__ cursor) {
    __shared__ int part[256];
    int t = threadIdx.x;
    const int chunk = (NNODES + 255) / 256;
    int i0 = t * chunk, i1 = i0 + chunk;
    if (i1 > NNODES) i1 = NNODES;
    int s = 0;
    for (int i = i0; i < i1; i++) s += deg[i];
    part[t] = s;
    __syncthreads();
    if (t == 0) {
        int acc = 0;
        for (int j = 0; j < 256; j++) { int v = part[j]; part[j] = acc; acc += v; }
    }
    __syncthreads();
    int acc = part[t];
    for (int i = i0; i < i1; i++) { start[i] = acc; cursor[i] = acc; acc += deg[i]; }
}

__global__ __launch_bounds__(256) void k_fill(const int* __restrict__ src, const int* __restrict__ dst,
                                              const int* __restrict__ et, int* __restrict__ cursor,
                                              int* __restrict__ csr) {
    int e = blockIdx.x * 256 + threadIdx.x;
    if (e >= NEDGES) return;
    int pos = atomicAdd(&cursor[dst[e]], 1);
    csr[pos] = src[e] * 8 + et[e];
}

// ---------------- fused prep: x->bf16, Brel/Broot/B2t transposes (block-aligned ranges) ----------------
#define PR0 (NNODES * 32)       // 640000  : x -> bf16, 8 elems each
#define PR1 (2048 * 256)        // 524288  : Brel
#define PR2 (256 * 256)         // 65536   : Broot
#define PR3 (1024 * 256)        // 262144  : B2t (+bias2)
__global__ __launch_bounds__(256) void k_prep(const float* __restrict__ x, const float* __restrict__ Wrel,
                                              const float* __restrict__ Wroot,
                                              const float* __restrict__ Wq, const float* __restrict__ Wk,
                                              const float* __restrict__ Wv, const float* __restrict__ Ws,
                                              const float* __restrict__ bq, const float* __restrict__ bk,
                                              const float* __restrict__ bv, const float* __restrict__ bs,
                                              unsigned short* __restrict__ xb, unsigned short* __restrict__ Brel,
                                              unsigned short* __restrict__ Broot, unsigned short* __restrict__ B2t,
                                              float* __restrict__ bias2) {
    int i = blockIdx.x * 256 + threadIdx.x;
    if (i < PR0) {
        const float4* p = (const float4*)(x + (size_t)i * 8);
        float4 v0 = p[0], v1 = p[1];
        u16x8 w;
        w[0] = f2bf(v0.x); w[1] = f2bf(v0.y); w[2] = f2bf(v0.z); w[3] = f2bf(v0.w);
        w[4] = f2bf(v1.x); w[5] = f2bf(v1.y); w[6] = f2bf(v1.z); w[7] = f2bf(v1.w);
        *(u16x8*)(xb + (size_t)i * 8) = w;
    } else if (i < PR0 + PR1) {
        int idx = i - PR0;
        int col = idx >> 8, g = idx & 255;
        int r = col >> 8, h = col & 255;
        Brel[idx] = f2bf(Wrel[(size_t)r * 65536 + (size_t)g * 256 + h]);
    } else if (i < PR0 + PR1 + PR2) {
        int idx = i - PR0 - PR1;
        int h = idx >> 8, g = idx & 255;
        Broot[idx] = f2bf(Wroot[(size_t)g * 256 + h]);
    } else {
        int idx = i - PR0 - PR1 - PR2;
        int c = idx >> 8, g = idx & 255;
        const float* W = (c < 256) ? Wq : (c < 512) ? Wk : (c < 768) ? Wv : Ws;
        int cc = c & 255;
        B2t[idx] = f2bf(W[(size_t)g * 256 + cc]);
        if (g == 0) {
            const float* B = (c < 256) ? bq : (c < 512) ? bk : (c < 768) ? bv : bs;
            bias2[c] = B[cc];
        }
    }
}

// ---------------- bf16 MFMA GEMM, A resident in LDS ----------------
template<int MODE>
__global__ __launch_bounds__(256) void k_gemm2(const unsigned short* __restrict__ A,
                                               const unsigned short* __restrict__ Bt,
                                               const float* __restrict__ bias, const float* __restrict__ addin,
                                               void* __restrict__ Cv, float* __restrict__ C2,
                                               int M, int Ncols, int cpb) {
    __shared__ unsigned short As[64][264];
    __shared__ unsigned short Bs[128][40];
    int tid = threadIdx.x;
    int lane = tid & 63, wid = tid >> 6;
    int wr = wid >> 1, wc = wid & 1;
    int lr = lane & 15, lq = lane >> 4;
    int brow = blockIdx.x * 64;
    int colBeg = blockIdx.y * cpb;

    {
        int row = tid >> 2;
        int cb = (tid & 3) * 64;
        int grow = brow + row;
        #pragma unroll
        for (int j = 0; j < 8; j++) {
            u16x8 v = {0, 0, 0, 0, 0, 0, 0, 0};
            if (grow < M) v = *(const u16x8*)(A + (size_t)grow * 256 + cb + j * 8);
            *(u16x8*)&As[row][cb + j * 8] = v;
        }
    }

    for (int bc = 0; bc < cpb; bc += 128) {
        int bcol = colBeg + bc;
        f32x4 acc[2][4];
        #pragma unroll
        for (int i = 0; i < 2; i++)
            #pragma unroll
            for (int j = 0; j < 4; j++) acc[i][j] = (f32x4){0.f, 0.f, 0.f, 0.f};

        for (int k0 = 0; k0 < 256; k0 += 32) {
            __syncthreads();
            {
                int r = tid >> 1, h = (tid & 1) * 16;
                const u16x8* p = (const u16x8*)(Bt + (size_t)(bcol + r) * 256 + k0 + h);
                *(u16x8*)&Bs[r][h] = p[0];
                *(u16x8*)&Bs[r][h + 8] = p[1];
            }
            __syncthreads();
            bf16x8 a0 = *(const bf16x8*)&As[wr * 32 + lr][k0 + lq * 8];
            bf16x8 a1 = *(const bf16x8*)&As[wr * 32 + 16 + lr][k0 + lq * 8];
            bf16x8 b0 = *(const bf16x8*)&Bs[wc * 64 + lr][lq * 8];
            bf16x8 b1 = *(const bf16x8*)&Bs[wc * 64 + 16 + lr][lq * 8];
            bf16x8 b2 = *(const bf16x8*)&Bs[wc * 64 + 32 + lr][lq * 8];
            bf16x8 b3 = *(const bf16x8*)&Bs[wc * 64 + 48 + lr][lq * 8];
            acc[0][0] = __builtin_amdgcn_mfma_f32_16x16x32_bf16(a0, b0, acc[0][0], 0, 0, 0);
            acc[0][1] = __builtin_amdgcn_mfma_f32_16x16x32_bf16(a0, b1, acc[0][1], 0, 0, 0);
            acc[0][2] = __builtin_amdgcn_mfma_f32_16x16x32_bf16(a0, b2, acc[0][2], 0, 0, 0);
            acc[0][3] = __builtin_amdgcn_mfma_f32_16x16x32_bf16(a0, b3, acc[0][3], 0, 0, 0);
            acc[1][0] = __builtin_amdgcn_mfma_f32_16x16x32_bf16(a1, b0, acc[1][0], 0, 0, 0);
            acc[1][1] = __builtin_amdgcn_mfma_f32_16x16x32_bf16(a1, b1, acc[1][1], 0, 0, 0);
            acc[1][2] = __builtin_amdgcn_mfma_f32_16x16x32_bf16(a1, b2, acc[1][2], 0, 0, 0);
            acc[1][3] = __builtin_amdgcn_mfma_f32_16x16x32_bf16(a1, b3, acc[1][3], 0, 0, 0);
        }

        #pragma unroll
        for (int rm = 0; rm < 2; rm++) {
            #pragma unroll
            for (int cn = 0; cn < 4; cn++) {
                int row = brow + wr * 32 + rm * 16 + lq * 4;
                int col = bcol + wc * 64 + cn * 16 + lr;
                #pragma unroll
                for (int r = 0; r < 4; r++) {
                    int gr = row + r;
                    if (gr >= M) continue;
                    float v = acc[rm][cn][r];
                    if (MODE == 2) {
                        ((unsigned short*)Cv)[(size_t)gr * Ncols + col] = f2bf(v);
                    } else if (MODE == 1) {
                        v += bias[col] + addin[(size_t)gr * 256 + col];
                        ((unsigned short*)Cv)[(size_t)gr * 256 + col] = f2bf(v);
                    } else {
                        v += bias[col];
                        if (col < 768) ((unsigned short*)Cv)[(size_t)gr * 768 + col] = f2bf(v);
                        else           C2[(size_t)gr * 256 + (col - 768)] = v;
                    }
                }
            }
        }
    }
}

// ---------------- RGCN aggregate: gather, one wave per dst node, edges batched x4 ----------------
__global__ __launch_bounds__(256) void k_rgcn(const unsigned short* __restrict__ Yall, const int* __restrict__ csr,
                                              const int* __restrict__ start, const int* __restrict__ deg,
                                              const float* __restrict__ inv, float* __restrict__ agg) {
    int node = blockIdx.x * 4 + (threadIdx.x >> 6);
    int lane = threadIdx.x & 63;
    if (node >= NNODES) return;
    int s0 = start[node], n = deg[node];
    float4 acc = make_float4(0.f, 0.f, 0.f, 0.f);
    int j = 0;
    for (; j + 4 <= n; j += 4) {
        int p0 = csr[s0 + j], p1 = csr[s0 + j + 1], p2 = csr[s0 + j + 2], p3 = csr[s0 + j + 3];
        float c0 = inv[node * RREL + (p0 & 7)];
        float c1 = inv[node * RREL + (p1 & 7)];
        float c2 = inv[node * RREL + (p2 & 7)];
        float c3 = inv[node * RREL + (p3 & 7)];
        ushort4 y0 = *(const ushort4*)(Yall + (size_t)(p0 >> 3) * 2048 + (p0 & 7) * 256 + lane * 4);
        ushort4 y1 = *(const ushort4*)(Yall + (size_t)(p1 >> 3) * 2048 + (p1 & 7) * 256 + lane * 4);
        ushort4 y2 = *(const ushort4*)(Yall + (size_t)(p2 >> 3) * 2048 + (p2 & 7) * 256 + lane * 4);
        ushort4 y3 = *(const ushort4*)(Yall + (size_t)(p3 >> 3) * 2048 + (p3 & 7) * 256 + lane * 4);
        acc.x += c0 * bf2f(y0.x) + c1 * bf2f(y1.x) + c2 * bf2f(y2.x) + c3 * bf2f(y3.x);
        acc.y += c0 * bf2f(y0.y) + c1 * bf2f(y1.y) + c2 * bf2f(y2.y) + c3 * bf2f(y3.y);
        acc.z += c0 * bf2f(y0.z) + c1 * bf2f(y1.z) + c2 * bf2f(y2.z) + c3 * bf2f(y3.z);
        acc.w += c0 * bf2f(y0.w) + c1 * bf2f(y1.w) + c2 * bf2f(y2.w) + c3 * bf2f(y3.w);
    }
    for (; j < n; j++) {
        int pk = csr[s0 + j];
        float sc = inv[node * RREL + (pk & 7)];
        ushort4 y = *(const ushort4*)(Yall + (size_t)(pk >> 3) * 2048 + (pk & 7) * 256 + lane * 4);
        acc.x += sc * bf2f(y.x);
        acc.y += sc * bf2f(y.y);
        acc.z += sc * bf2f(y.z);
        acc.w += sc * bf2f(y.w);
    }
    ((float4*)(agg + (size_t)node * 256))[lane] = acc;
}

// ---------------- fused attention: one wave per node, online softmax, edges batched x4 ----------------
__global__ __launch_bounds__(256) void k_attn(const unsigned short* __restrict__ QKV, const int* __restrict__ csr,
                                              const int* __restrict__ start, const int* __restrict__ deg,
                                              float* __restrict__ out) {
    int node = blockIdx.x * 4 + (threadIdx.x >> 6);
    int lane = threadIdx.x & 63;
    if (node >= NNODES) return;
    int s0 = start[node], n = deg[node];
    if (n == 0) return;
    ushort4 qu = *(const ushort4*)(QKV + (size_t)node * 768 + lane * 4);
    float q0 = bf2f(qu.x), q1 = bf2f(qu.y), q2 = bf2f(qu.z), q3 = bf2f(qu.w);
    float m = -INFINITY, den = 0.f;
    float4 acc = make_float4(0.f, 0.f, 0.f, 0.f);
    int j = 0;
    for (; j + 4 <= n; j += 4) {
        const unsigned short* b0 = QKV + (size_t)(csr[s0 + j] >> 3) * 768;
        const unsigned short* b1 = QKV + (size_t)(csr[s0 + j + 1] >> 3) * 768;
        const unsigned short* b2 = QKV + (size_t)(csr[s0 + j + 2] >> 3) * 768;
        const unsigned short* b3 = QKV + (size_t)(csr[s0 + j + 3] >> 3) * 768;
        ushort4 k0 = *(const ushort4*)(b0 + 256 + lane * 4);
        ushort4 k1 = *(const ushort4*)(b1 + 256 + lane * 4);
        ushort4 k2 = *(const ushort4*)(b2 + 256 + lane * 4);
        ushort4 k3 = *(const ushort4*)(b3 + 256 + lane * 4);
        ushort4 v0 = *(const ushort4*)(b0 + 512 + lane * 4);
        ushort4 v1 = *(const ushort4*)(b1 + 512 + lane * 4);
        ushort4 v2 = *(const ushort4*)(b2 + 512 + lane * 4);
        ushort4 v3 = *(const ushort4*)(b3 + 512 + lane * 4);
        float p0 = q0 * bf2f(k0.x) + q1 * bf2f(k0.y) + q2 * bf2f(k0.z) + q3 * bf2f(k0.w);
        float p1 = q0 * bf2f(k1.x) + q1 * bf2f(k1.y) + q2 * bf2f(k1.z) + q3 * bf2f(k1.w);
        float p2 = q0 * bf2f(k2.x) + q1 * bf2f(k2.y) + q2 * bf2f(k2.z) + q3 * bf2f(k2.w);
        float p3 = q0 * bf2f(k3.x) + q1 * bf2f(k3.y) + q2 * bf2f(k3.z) + q3 * bf2f(k3.w);
        #pragma unroll
        for (int o = 32; o; o >>= 1) {
            p0 += __shfl_xor(p0, o);
            p1 += __shfl_xor(p1, o);
            p2 += __shfl_xor(p2, o);
            p3 += __shfl_xor(p3, o);
        }
        p0 *= 0.0625f; p1 *= 0.0625f; p2 *= 0.0625f; p3 *= 0.0625f;
        float pm = fmaxf(fmaxf(p0, p1), fmaxf(p2, p3));
        if (pm > m) {
            float rr = __expf(m - pm);   // first batch: exp(-inf)=0
            den *= rr;
            acc.x *= rr; acc.y *= rr; acc.z *= rr; acc.w *= rr;
            m = pm;
        }
        float e0 = __expf(p0 - m), e1 = __expf(p1 - m), e2 = __expf(p2 - m), e3 = __expf(p3 - m);
        den += e0 + e1 + e2 + e3;
        acc.x += e0 * bf2f(v0.x) + e1 * bf2f(v1.x) + e2 * bf2f(v2.x) + e3 * bf2f(v3.x);
        acc.y += e0 * bf2f(v0.y) + e1 * bf2f(v1.y) + e2 * bf2f(v2.y) + e3 * bf2f(v3.y);
        acc.z += e0 * bf2f(v0.z) + e1 * bf2f(v1.z) + e2 * bf2f(v2.z) + e3 * bf2f(v3.z);
        acc.w += e0 * bf2f(v0.w) + e1 * bf2f(v1.w) + e2 * bf2f(v2.w) + e3 * bf2f(v3.w);
    }
    for (; j < n; j++) {
        const unsigned short* base = QKV + (size_t)(csr[s0 + j] >> 3) * 768;
        ushort4 ku = *(const ushort4*)(base + 256 + lane * 4);
        ushort4 vu = *(const ushort4*)(base + 512 + lane * 4);
        float p = q0 * bf2f(ku.x) + q1 * bf2f(ku.y) + q2 * bf2f(ku.z) + q3 * bf2f(ku.w);
        #pragma unroll
        for (int o = 32; o; o >>= 1) p += __shfl_xor(p, o);
        p *= 0.0625f;
        if (p > m) {
            float rr = __expf(m - p);
            den *= rr;
            acc.x *= rr; acc.y *= rr; acc.z *= rr; acc.w *= rr;
            m = p;
        }
        float ex = __expf(p - m);
        den += ex;
        acc.x += ex * bf2f(vu.x); acc.y += ex * bf2f(vu.y);
        acc.z += ex * bf2f(vu.z); acc.w += ex * bf2f(vu.w);
    }
    float rinv = 1.0f / fmaxf(den, 1e-16f);
    float4* o4 = (float4*)(out + (size_t)node * 256);
    float4 o = o4[lane];
    o.x += acc.x * rinv; o.y += acc.y * rinv; o.z += acc.z * rinv; o.w += acc.w * rinv;
    o4[lane] = o;
}

// ---------------- batch norm + leaky relu ----------------
__global__ __launch_bounds__(256) void k_bnstats(const float* __restrict__ out, float* __restrict__ sums,
                                                 float* __restrict__ sumsq) {
    int c = threadIdx.x;
    int rows_per = (NNODES + gridDim.x - 1) / gridDim.x;
    int r0 = blockIdx.x * rows_per;
    int r1 = r0 + rows_per; if (r1 > NNODES) r1 = NNODES;
    float s = 0.f, ss = 0.f;
    for (int r = r0; r < r1; r++) {
        float v = out[(size_t)r * 256 + c];
        s += v; ss += v * v;
    }
    atomicAdd(&sums[c], s);
    atomicAdd(&sumsq[c], ss);
}

// scale/shift recomputed per thread from sums (2KB L2-resident) — bnfinal folded in
__global__ __launch_bounds__(256) void k_bnapply(float4* __restrict__ out, const float* __restrict__ sums,
                                                 const float* __restrict__ sumsq, const float* __restrict__ gamma,
                                                 const float* __restrict__ beta) {
    int i = blockIdx.x * 256 + threadIdx.x;
    if (i >= NNODES * 64) return;
    int c4 = i & 63;
    float4 sc, sh;
    #pragma unroll
    for (int t = 0; t < 4; t++) {
        int c = c4 * 4 + t;
        float mu = sums[c] * (1.0f / NNODES);
        float var = sumsq[c] * (1.0f / NNODES) - mu * mu;
        float s = gamma[c] * rsqrtf(fmaxf(var, 0.f) + EPSBN);
        ((float*)&sc)[t] = s;
        ((float*)&sh)[t] = beta[c] - mu * s;
    }
    float4 v = out[i];
    v.x = v.x * sc.x + sh.x; v.y = v.y * sc.y + sh.y;
    v.z = v.z * sc.z + sh.z; v.w = v.w * sc.w + sh.w;
    v.x = v.x > 0.f ? v.x : 0.01f * v.x;
    v.y = v.y > 0.f ? v.y : 0.01f * v.y;
    v.z = v.z > 0.f ? v.z : 0.01f * v.z;
    v.w = v.w > 0.f ? v.w : 0.01f * v.w;
    out[i] = v;
}

extern "C" void kernel_launch(void* const* d_in, const int* in_sizes, int n_in,
                              void* d_out, int out_size, void* d_ws, size_t ws_size,
                              hipStream_t stream) {
    const float* x = (const float*)d_in[0];
    const int* ei = (const int*)d_in[1];
    const int* etype = (const int*)d_in[2];
    const float* Wrel = (const float*)d_in[3];
    const float* Wroot = (const float*)d_in[4];
    const float* b1 = (const float*)d_in[5];
    const float* Wq = (const float*)d_in[6];
    const float* bq = (const float*)d_in[7];
    const float* Wk = (const float*)d_in[8];
    const float* bk = (const float*)d_in[9];
    const float* Wv = (const float*)d_in[10];
    const float* bv = (const float*)d_in[11];
    const float* Ws = (const float*)d_in[12];
    const float* bs = (const float*)d_in[13];
    const float* gamma = (const float*)d_in[14];
    const float* beta = (const float*)d_in[15];
    float* out = (float*)d_out;

    const int* srcA = ei;
    const int* dstA = ei + NEDGES;

    char* w = (char*)d_ws;
    unsigned short* Yall = (unsigned short*)w;  w += (size_t)NNODES * 2048 * 2;
    unsigned short* x_bf = (unsigned short*)w;  w += (size_t)NNODES * 256 * 2;
    unsigned short* x1bf = (unsigned short*)w;  w += (size_t)NNODES * 256 * 2;
    float* agg = (float*)w;                     w += (size_t)NNODES * 256 * 4;
    unsigned short* QKVbf = (unsigned short*)w; w += (size_t)NNODES * 768 * 2;
    unsigned short* Brel = (unsigned short*)w;  w += (size_t)2048 * 256 * 2;
    unsigned short* Broot = (unsigned short*)w; w += (size_t)256 * 256 * 2;
    unsigned short* B2t = (unsigned short*)w;   w += (size_t)1024 * 256 * 2;
    float* bias2 = (float*)w;                   w += 1024 * 4;
    int* cnt = (int*)w;                         w += (size_t)NNODES * RREL * 4;
    float* invc = (float*)w;                    w += (size_t)NNODES * RREL * 4;
    int* deg = (int*)w;                         w += (size_t)NNODES * 4;
    int* startv = (int*)w;                      w += (size_t)NNODES * 4;
    int* cursor = (int*)w;                      w += (size_t)NNODES * 4;
    int* csr = (int*)w;                         w += (size_t)NEDGES * 4;
    float* sums = (float*)w;                    w += 1024;
    float* sumsq = (float*)w;                   w += 1024;
    size_t need = (size_t)(w - (char*)d_ws);
    if (ws_size < need) return;

    hipMemsetAsync(cnt, 0, (size_t)NNODES * RREL * 4, stream);
    hipMemsetAsync(sums, 0, 2048, stream);

    k_count<<<(NEDGES + 255) / 256, 256, 0, stream>>>(dstA, etype, cnt);
    k_invdeg<<<(NNODES + 255) / 256, 256, 0, stream>>>(cnt, invc, deg);
    k_scan<<<1, 256, 0, stream>>>(deg, startv, cursor);
    k_fill<<<(NEDGES + 255) / 256, 256, 0, stream>>>(srcA, dstA, etype, cursor, csr);

    k_prep<<<(PR0 + PR1 + PR2 + PR3) / 256, 256, 0, stream>>>(x, Wrel, Wroot, Wq, Wk, Wv, Ws,
                                                              bq, bk, bv, bs, x_bf, Brel, Broot, B2t, bias2);

    k_gemm2<2><<<dim3(313, 4), 256, 0, stream>>>(x_bf, Brel, nullptr, nullptr, (void*)Yall, nullptr,
                                                 NNODES, 2048, 512);

    k_rgcn<<<(NNODES + 3) / 4, 256, 0, stream>>>(Yall, csr, startv, deg, invc, agg);

    k_gemm2<1><<<dim3(313, 2), 256, 0, stream>>>(x_bf, Broot, b1, agg, (void*)x1bf, nullptr,
                                                 NNODES, 256, 128);

    k_gemm2<3><<<dim3(313, 4), 256, 0, stream>>>(x1bf, B2t, bias2, nullptr, (void*)QKVbf, out,
                                                 NNODES, 1024, 256);

    k_attn<<<(NNODES + 3) / 4, 256, 0, stream>>>(QKVbf, csr, startv, deg, out);

    k_bnstats<<<200, 256, 0, stream>>>(out, sums, sumsq);
    k_bnapply<<<(NNODES * 64 + 255) / 256, 256, 0, stream>>>((float4*)out, sums, sumsq, gamma, beta);
}